// Round 12
// baseline (536.915 us; speedup 1.0000x reference)
//
#include <hip/hip_runtime.h>
#include <math.h>

namespace {

constexpr int Bb = 4, Ss = 256, Dd = 768, Vv = 50257;
constexpr int Mm = Bb * Ss;               // 1024 rows
constexpr int BM = 256, BN = 256, BK = 32;
constexpr int NS = Dd / BK;               // 24 k-steps
constexpr int TW = (Vv + BN - 1) / BN;    // 197 W tiles (last padded w/ zeros)
constexpr int TA = Mm / BM;               // 4 A tiles
constexpr int NT4 = TW * 4;               // 788 per-row partial slices (64 cols each)
constexpr int CH = BN * BK;               // 8192 f16 per plane-chunk (16 KB)
constexpr float SC = 14.4269504088896341f;   // 10 * log2(e)

// epilogue partial arrays (union over staging LDS): [256 rows][4 wc][5 pad]
constexpr int PSTRIDE = 5;
constexpr int PC = 256 * 4 * PSTRIDE;     // 5120 entries per array (61440 B x3 total)

typedef _Float16 f16x8 __attribute__((ext_vector_type(8)));
typedef float f32x4 __attribute__((ext_vector_type(4)));

// Packed scratch (inside out3 region; finalize one-hot overwrites it LAST):
//   Whp, Wlp [TW*NS*CH], Ahp, Alp [TA*NS*CH], tsq[Vv], asq[Mm],
//   pmax/pidx/psum [Mm*NT4]
constexpr size_t WPLANE = (size_t)TW * NS * CH;   // 38,731,776 f16
constexpr size_t APLANE = (size_t)TA * NS * CH;   //    786,432 f16
// bytes: 2*(WPLANE+APLANE)*2 + (Vv+Mm)*4 + 3*Mm*NT4*4 ≈ 168.0 MB < 205.8 MB

__device__ __forceinline__ void gload_lds16(const void* g, void* l) {
    typedef __attribute__((address_space(3))) void lds_t;
    typedef const __attribute__((address_space(1))) void gm_t;
    __builtin_amdgcn_global_load_lds((gm_t*)g, (lds_t*)l, 16, 0, 0);
}

// ---------------------------------------------------------------------------
// Kernel 1: fused split-convert + pack + row-sumsq (R9/R10-verified per-thread
// logic), 256-row tiles for both W and A. grid (TW+TA, 4 bands).
// Thread: rr = band*64 + (tid>>2), quarter q = tid&3 -> steps q*6..q*6+5.
// Rows >= nrows pack as zeros (kills GEMM bounds checks).
// ---------------------------------------------------------------------------
__global__ __launch_bounds__(256) void convert_pack_tsq(const float* __restrict__ srcW,
                                                        const float* __restrict__ srcA,
                                                        _Float16* __restrict__ Whp,
                                                        _Float16* __restrict__ Wlp,
                                                        _Float16* __restrict__ Ahp,
                                                        _Float16* __restrict__ Alp,
                                                        float* __restrict__ tsq,
                                                        float* __restrict__ asq) {
    const bool isW = blockIdx.x < TW;
    const int t    = isW ? blockIdx.x : (blockIdx.x - TW);
    const int nrows = isW ? Vv : Mm;
    const float* __restrict__ src = isW ? srcW : srcA;
    _Float16* __restrict__ hp = isW ? Whp : Ahp;
    _Float16* __restrict__ lp = isW ? Wlp : Alp;
    float* __restrict__ sumsq = isW ? tsq : asq;

    const int tid = threadIdx.x;
    const int rr  = blockIdx.y * 64 + (tid >> 2);   // 0..255 tile row
    const int q   = tid & 3;                        // step quarter
    const int v   = t * BM + rr;
    const bool valid = v < nrows;

    float sq = 0.f;
#pragma unroll
    for (int i = 0; i < 6; ++i) {
        const int s = q * 6 + i;
        float vals[32];
        if (valid) {
            const float4* p = reinterpret_cast<const float4*>(src + (size_t)v * Dd + s * BK);
#pragma unroll
            for (int k = 0; k < 8; ++k) *reinterpret_cast<float4*>(&vals[4 * k]) = p[k];
        } else {
#pragma unroll
            for (int k = 0; k < 32; ++k) vals[k] = 0.f;
        }
        const size_t chunk = ((size_t)t * NS + s) * CH;
#pragma unroll
        for (int fq = 0; fq < 4; ++fq) {
            _Float16 hi8[8], lo8[8];
#pragma unroll
            for (int e = 0; e < 8; ++e) {
                const float x = vals[fq * 8 + e];
                sq = fmaf(x, x, sq);
                const _Float16 h = (_Float16)x;
                hi8[e] = h;
                lo8[e] = (_Float16)(x - (float)h);
            }
            *reinterpret_cast<f16x8*>(&hp[chunk + fq * (BM * 8) + (size_t)rr * 8]) =
                *reinterpret_cast<const f16x8*>(hi8);
            *reinterpret_cast<f16x8*>(&lp[chunk + fq * (BM * 8) + (size_t)rr * 8]) =
                *reinterpret_cast<const f16x8*>(lo8);
        }
    }
    sq += __shfl_xor(sq, 1);
    sq += __shfl_xor(sq, 2);
    if (valid && q == 0) sumsq[v] = sq;
}

// ---------------------------------------------------------------------------
// Kernel 2: scores = 2*(A.W^T) - tsq. 256x256 tile, 8 waves (2M x 4N),
// DOUBLE-BUFFERED LDS + COUNTED vmcnt(8) pipeline (T3+T4): next step's
// global_load_lds stays in flight across both barriers; never drained to 0
// in-loop. Per-wave 64-col fragment geometry identical to R5/R11-verified.
// Epilogue: depth-2 shfl pre-merge (R8 math) + LDS merge (R7 pattern).
// ---------------------------------------------------------------------------
__global__ __launch_bounds__(512) void gemm_kernel(const _Float16* __restrict__ Ahp,
                                                   const _Float16* __restrict__ Alp,
                                                   const _Float16* __restrict__ Whp,
                                                   const _Float16* __restrict__ Wlp,
                                                   const float* __restrict__ tsq,
                                                   float* __restrict__ scores,
                                                   float* __restrict__ pmax,
                                                   int*   __restrict__ pidx,
                                                   float* __restrict__ psum) {
    __shared__ _Float16 lds[2][4][CH];    // 2 bufs x {Ah,Al,Wh,Wl} x 16KB = 128 KB

    // bijective XCD chunking over 197 W tiles x 4 A tiles
    const int b    = blockIdx.x;
    const int xcd  = b & 7;
    const int slot = b >> 3;              // 0..99
    const int ltn  = slot >> 2;           // 0..24
    const int tm   = slot & 3;
    const int cnt  = (xcd < 5) ? 25 : 24;
    if (ltn >= cnt) return;
    const int tn   = ((xcd < 5) ? 25 * xcd : 125 + 24 * (xcd - 5)) + ltn;

    const int tid  = threadIdx.x;
    const int wid  = tid >> 6;            // 0..7
    const int lane = tid & 63;
    const int wr   = wid >> 2;            // wave row (0..1) -> 128 rows
    const int wc   = wid & 3;             // wave col (0..3) -> 64 cols
    const int fr   = lane & 15;
    const int fq   = lane >> 4;

    const _Float16* gA_h = Ahp + (size_t)tm * NS * CH;
    const _Float16* gA_l = Alp + (size_t)tm * NS * CH;
    const _Float16* gW_h = Whp + (size_t)tn * NS * CH;
    const _Float16* gW_l = Wlp + (size_t)tn * NS * CH;

    // staging role: wave wid loads plane (wid>>1), segment half (wid&1)
    const int pl  = wid >> 1;                       // 0:Ah 1:Al 2:Wh 3:Wl
    const int j0  = (wid & 1) * 8;                  // segment base 0 or 8
    const _Float16* myplane = (pl == 0) ? gA_h : (pl == 1) ? gA_l
                            : (pl == 2) ? gW_h : gW_l;

    auto STAGE = [&](int s, int bf) {
        const _Float16* base = myplane + (size_t)s * CH;
        _Float16* dst = &lds[bf][pl][0];
#pragma unroll
        for (int k = 0; k < 8; ++k) {
            const int j = j0 + k;
            gload_lds16(base + j * 512 + lane * 8, dst + j * 512);
        }
    };

    f32x4 acc[8][4];
#pragma unroll
    for (int m = 0; m < 8; ++m)
#pragma unroll
        for (int n = 0; n < 4; ++n) acc[m][n] = (f32x4){0.f, 0.f, 0.f, 0.f};

    STAGE(0, 0);
    for (int s = 0; s < NS; ++s) {
        const int cur = s & 1;
        if (s + 1 < NS) {
            STAGE(s + 1, cur ^ 1);                       // issue next step's loads
            asm volatile("s_waitcnt vmcnt(8)" ::: "memory");  // wait STAGE(s) only
        } else {
            asm volatile("s_waitcnt vmcnt(0)" ::: "memory");  // final drain
        }
        __builtin_amdgcn_s_barrier();                    // buf[cur] collectively ready

        const _Float16* Lb = &lds[cur][0][0];
        f16x8 ah[8], al[8];
#pragma unroll
        for (int m = 0; m < 8; ++m) {
            const int row = wr * 128 + m * 16 + fr;
            ah[m] = *reinterpret_cast<const f16x8*>(&Lb[0 * CH + fq * 2048 + row * 8]);
            al[m] = *reinterpret_cast<const f16x8*>(&Lb[1 * CH + fq * 2048 + row * 8]);
        }
#pragma unroll
        for (int n = 0; n < 4; ++n) {
            const int col = wc * 64 + n * 16 + fr;
            const f16x8 wh = *reinterpret_cast<const f16x8*>(&Lb[2 * CH + fq * 2048 + col * 8]);
            const f16x8 wl = *reinterpret_cast<const f16x8*>(&Lb[3 * CH + fq * 2048 + col * 8]);
#pragma unroll
            for (int m = 0; m < 8; ++m) {
                acc[m][n] = __builtin_amdgcn_mfma_f32_16x16x32_f16(ah[m], wh, acc[m][n], 0, 0, 0);
                acc[m][n] = __builtin_amdgcn_mfma_f32_16x16x32_f16(al[m], wh, acc[m][n], 0, 0, 0);
                acc[m][n] = __builtin_amdgcn_mfma_f32_16x16x32_f16(ah[m], wl, acc[m][n], 0, 0, 0);
            }
        }
        __builtin_amdgcn_s_barrier();                    // reads of buf[cur] done
        asm volatile("" ::: "memory");
    }

    // ------------- epilogue: score stores + partials -------------
    __syncthreads();                      // full fence: staging LDS now reusable
    float* pmL = reinterpret_cast<float*>(&lds[0][0][0]);
    float* psL = pmL + PC;
    int*   piL = reinterpret_cast<int*>(psL + PC);

    float tq[4];
    int   gcol[4];
    bool  ok[4];
#pragma unroll
    for (int n = 0; n < 4; ++n) {
        gcol[n] = tn * BN + wc * 64 + n * 16 + fr;
        ok[n]   = gcol[n] < Vv;
        tq[n]   = ok[n] ? tsq[gcol[n]] : 0.f;
    }

#pragma unroll
    for (int m = 0; m < 8; ++m) {
#pragma unroll
        for (int r = 0; r < 4; ++r) {
            const int rloc = wr * 128 + m * 16 + fq * 4 + r;
            const int grow = tm * BM + rloc;
            float sv[4];
            float vmax = -INFINITY;
            int   vidx = 0x7fffffff;
#pragma unroll
            for (int n = 0; n < 4; ++n) {
                sv[n] = ok[n] ? fmaf(2.f, acc[m][n][r], -tq[n]) : -INFINITY;
                if (ok[n]) {
                    scores[(size_t)grow * Vv + gcol[n]] = sv[n];
                    if (sv[n] > vmax) { vmax = sv[n]; vidx = gcol[n]; }  // ascending gn
                }
            }
            float ls = 0.f;
            if (vmax > -INFINITY) {
#pragma unroll
                for (int n = 0; n < 4; ++n)
                    if (ok[n]) ls += exp2f((sv[n] - vmax) * SC);
            }
            // depth-2 merge across fr^1, fr^2 (R8-verified math)
#pragma unroll
            for (int off = 1; off <= 2; off <<= 1) {
                const float om = __shfl_xor(vmax, off);
                const int   oi = __shfl_xor(vidx, off);
                const float os = __shfl_xor(ls,  off);
                if (om > vmax || (om == vmax && om > -INFINITY && oi < vidx)) {
                    ls = ((vmax > -INFINITY) ? ls * exp2f((vmax - om) * SC) : 0.f) + os;
                    vmax = om; vidx = oi;
                } else if (om > -INFINITY) {
                    ls += os * exp2f((om - vmax) * SC);
                }
            }
            if ((fr & 3) == 0) {
                const int o = (rloc * 4 + wc) * PSTRIDE + (fr >> 2);
                pmL[o] = vmax;
                psL[o] = ls;
                piL[o] = vidx;
            }
        }
    }
    __syncthreads();

    // merge 4 quad-partials per (row, wc-slice); 1024 slices, 512 threads
    for (int u = tid; u < 256 * 4; u += 512) {
        const int rloc = u >> 2;
        const int wcs  = u & 3;
        float m = -INFINITY, s = 0.f;
        int   id = 0x7fffffff;
#pragma unroll
        for (int f = 0; f < 4; ++f) {
            const int o = (rloc * 4 + wcs) * PSTRIDE + f;
            const float m2 = pmL[o];
            const int   i2 = piL[o];
            const float s2 = psL[o];
            if (m2 > m || (m2 == m && m2 > -INFINITY && i2 < id)) {
                s = ((m > -INFINITY) ? s * exp2f((m - m2) * SC) : 0.f) + s2;
                m = m2; id = i2;
            } else if (m2 > -INFINITY) {
                s += s2 * exp2f((m2 - m) * SC);
            }
        }
        const int grow = tm * BM + rloc;
        const int cidx = tn * 4 + wcs;
        const size_t o = (size_t)grow * NT4 + cidx;
        pmax[o] = m;
        pidx[o] = id;
        psum[o] = s;
    }
}

// ---------------------------------------------------------------------------
// Kernel 3: finalize with integrated per-row stats reduce (R11-verified) +
// single-pass writeout: probs + one-hot + gather W[pred] + copy A row.
// ---------------------------------------------------------------------------
__global__ __launch_bounds__(256) void finalize_kernel(const float* __restrict__ A,
                                                       const float* __restrict__ W,
                                                       const float* __restrict__ pmax,
                                                       const int*   __restrict__ pidx,
                                                       const float* __restrict__ psum,
                                                       float* __restrict__ out0,
                                                       float* __restrict__ out1,
                                                       float* __restrict__ out2,
                                                       float* __restrict__ out3,
                                                       float* __restrict__ out4) {
    const int row = blockIdx.x;
    const int tid = threadIdx.x;
    float* srow = out4 + (size_t)row * Vv;
    float* hrow = out3 + (size_t)row * Vv;
    constexpr int NV4 = Vv >> 2;

    // ---- per-row stats reduce over NT4=788 partials ----
    const size_t base = (size_t)row * NT4;
    float m = -INFINITY, s = 0.f;
    int   id = 0x7fffffff;
    for (int c = tid; c < NT4; c += 256) {
        const float m2 = pmax[base + c];
        const int   i2 = pidx[base + c];
        const float s2 = psum[base + c];
        if (m2 > m || (m2 == m && m2 > -INFINITY && i2 < id)) {
            s = ((m > -INFINITY) ? s * exp2f((m - m2) * SC) : 0.f) + s2;
            m = m2; id = i2;
        } else if (m2 > -INFINITY) {
            s += s2 * exp2f((m2 - m) * SC);
        }
    }
    __shared__ float smax[256];
    __shared__ int   sidx[256];
    __shared__ float ssum[256];
    smax[tid] = m; sidx[tid] = id; ssum[tid] = s;
    __syncthreads();
#pragma unroll
    for (int off = 128; off > 0; off >>= 1) {
        if (tid < off) {
            const float m1 = smax[tid], m2 = smax[tid + off];
            const int   i1 = sidx[tid], i2 = sidx[tid + off];
            const float s1 = ssum[tid], s2 = ssum[tid + off];
            if (m2 > m1 || (m2 == m1 && m2 > -INFINITY && i2 < i1)) {
                smax[tid] = m2; sidx[tid] = i2;
                ssum[tid] = ((m1 > -INFINITY) ? s1 * exp2f((m1 - m2) * SC) : 0.f) + s2;
            } else if (m2 > -INFINITY) {
                ssum[tid] = s1 + s2 * exp2f((m2 - m1) * SC);
            }
        }
        __syncthreads();
    }
    const float gmax = smax[0];
    const int   pred = sidx[0];
    const float inv  = 1.0f / ssum[0];
    __syncthreads();

    // ---- single-pass writeout ----
    const float4* s4 = reinterpret_cast<const float4*>(srow);
    float4* p4 = reinterpret_cast<float4*>(srow);
    float4* h4 = reinterpret_cast<float4*>(hrow);
    for (int i = tid; i < NV4; i += 256) {
        const float4 v = s4[i];
        const int b = 4 * i;
        float4 p, h;
        p.x = exp2f((v.x - gmax) * SC) * inv;
        p.y = exp2f((v.y - gmax) * SC) * inv;
        p.z = exp2f((v.z - gmax) * SC) * inv;
        p.w = exp2f((v.w - gmax) * SC) * inv;
        h.x = (b + 0 == pred) ? 1.f : 0.f;
        h.y = (b + 1 == pred) ? 1.f : 0.f;
        h.z = (b + 2 == pred) ? 1.f : 0.f;
        h.w = (b + 3 == pred) ? 1.f : 0.f;
        p4[i] = p;
        h4[i] = h;
    }
    if (tid == 0) {
        const float val = srow[Vv - 1];
        srow[Vv - 1] = exp2f((val - gmax) * SC) * inv;
        hrow[Vv - 1] = (pred == Vv - 1) ? 1.f : 0.f;
        out2[row] = (float)pred;
    }

    const float4* wrow = reinterpret_cast<const float4*>(W + (size_t)pred * Dd);
    const float4* arow = reinterpret_cast<const float4*>(A + (size_t)row * Dd);
    float4* o0 = reinterpret_cast<float4*>(out0 + (size_t)row * Dd);
    float4* o1 = reinterpret_cast<float4*>(out1 + (size_t)row * Dd);
    if (tid < Dd / 4) {
        o0[tid] = wrow[tid];
        o1[tid] = arow[tid];
    }
}

}  // namespace

extern "C" void kernel_launch(void* const* d_in, const int* in_sizes, int n_in,
                              void* d_out, int out_size, void* d_ws, size_t ws_size,
                              hipStream_t stream) {
    const float* pred_embeds  = (const float*)d_in[0];   // (4,256,768)
    const float* embed_weight = (const float*)d_in[1];   // (50257,768)

    float* out  = (float*)d_out;
    float* out0 = out;                                    // (B,S,D)
    float* out1 = out0 + (size_t)Mm * Dd;                 // (B,S,D)
    float* out2 = out1 + (size_t)Mm * Dd;                 // (B,S)
    float* out3 = out2 + Mm;                              // (B,S,V) one-hot (scratch until finalize)
    float* out4 = out3 + (size_t)Mm * Vv;                 // (B,S,V) probs (scores until finalize)

    // packed scratch inside the out3 region
    _Float16* Whp = (_Float16*)out3;
    _Float16* Wlp = Whp + WPLANE;
    _Float16* Ahp = Wlp + WPLANE;
    _Float16* Alp = Ahp + APLANE;
    float*    tsq = (float*)(Alp + APLANE);
    float*    asq = tsq + Vv;                             // A row-sumsq (unused)
    float*    pmax = asq + Mm;
    int*      pidx = (int*)(pmax + (size_t)Mm * NT4);
    float*    psum = (float*)(pidx + (size_t)Mm * NT4);

    convert_pack_tsq<<<dim3(TW + TA, 4), 256, 0, stream>>>(embed_weight, pred_embeds,
                                                           Whp, Wlp, Ahp, Alp, tsq, asq);

    gemm_kernel<<<800, 512, 0, stream>>>(Ahp, Alp, Whp, Wlp, tsq, out4,
                                         pmax, pidx, psum);

    finalize_kernel<<<Mm, 256, 0, stream>>>(pred_embeds, embed_weight,
                                            pmax, pidx, psum,
                                            out0, out1, out2, out3, out4);
}

// Round 13
// 485.977 us; speedup vs baseline: 1.1048x; 1.1048x over previous
//
#include <hip/hip_runtime.h>
#include <math.h>

namespace {

constexpr int Bb = 4, Ss = 256, Dd = 768, Vv = 50257;
constexpr int Mm = Bb * Ss;               // 1024 rows
constexpr int BM = 128, BN = 128, BK = 32;
constexpr int NS = Dd / BK;               // 24 k-steps
constexpr int TW = (Vv + BN - 1) / BN;    // 393 W tiles (last padded w/ zeros)
constexpr int TA = Mm / BM;               // 8 A tiles
constexpr int NT2 = TW * 2;               // 786 per-row partial slices (64 cols each)
constexpr int CHUNK = BM * BK;            // 4096 f16 = 8 KB per (tile, step) per plane
constexpr float SC = 14.4269504088896341f;   // 10 * log2(e)

// LDS partial arrays: [128 rows][2 wc][17 fr-padded]  (pad kills bank conflicts)
constexpr int PSTRIDE = 17;
constexpr int PCOUNT  = 128 * 2 * PSTRIDE;         // 4352 entries per array
constexpr size_t SMEM_BYTES = (size_t)PCOUNT * 4 * 3;  // 52224 B > 32768 B staging

typedef _Float16 f16x8 __attribute__((ext_vector_type(8)));
typedef float f32x4 __attribute__((ext_vector_type(4)));

// Packed scratch layout (inside out3 region; finalize's one-hot overwrites it
// LAST — nothing reads scratch after finalize's writeout begins):
//   Whp, Wlp, Ahp, Alp, tsq[Vv], asq[Mm], pmax[Mm*NT2], pidx[Mm*NT2], psum[Mm*NT2]
constexpr size_t WPLANE = (size_t)TW * NS * CHUNK;   // 38,633,472 f16
constexpr size_t APLANE = (size_t)TA * NS * CHUNK;   //    786,432 f16
// bytes: 2*(WPLANE+APLANE)*2 + (Vv+Mm)*4 + 3*Mm*NT2*4 = ~167.5 MB < 205.8 MB

__device__ __forceinline__ void gload_lds16(const void* g, void* l) {
    typedef __attribute__((address_space(3))) void lds_t;
    typedef const __attribute__((address_space(1))) void gm_t;
    __builtin_amdgcn_global_load_lds((gm_t*)g, (lds_t*)l, 16, 0, 0);
}

// ---------------------------------------------------------------------------
// Kernel 1: fused split-convert + pack + row-sumsq (R9-verified).
// ONE launch for both matrices: bx < TW -> W tile bx; else A tile (bx - TW).
// Thread: row = by*64 + (tid>>2), quarter q = tid&3 handles steps q*6..q*6+5.
// Rows >= nrows pack as zeros (kills GEMM bounds checks).
// ---------------------------------------------------------------------------
__global__ __launch_bounds__(256) void convert_pack_tsq(const float* __restrict__ srcW,
                                                        const float* __restrict__ srcA,
                                                        _Float16* __restrict__ Whp,
                                                        _Float16* __restrict__ Wlp,
                                                        _Float16* __restrict__ Ahp,
                                                        _Float16* __restrict__ Alp,
                                                        float* __restrict__ tsq,
                                                        float* __restrict__ asq) {
    const bool isW = blockIdx.x < TW;
    const int t    = isW ? blockIdx.x : (blockIdx.x - TW);
    const int nrows = isW ? Vv : Mm;
    const float* __restrict__ src = isW ? srcW : srcA;
    _Float16* __restrict__ hp = isW ? Whp : Ahp;
    _Float16* __restrict__ lp = isW ? Wlp : Alp;
    float* __restrict__ sumsq = isW ? tsq : asq;

    const int tid = threadIdx.x;
    const int r   = blockIdx.y * 64 + (tid >> 2);   // 0..127 tile row
    const int q   = tid & 3;                        // step quarter
    const int v   = t * BM + r;
    const bool valid = v < nrows;

    float sq = 0.f;
#pragma unroll
    for (int i = 0; i < 6; ++i) {
        const int s = q * 6 + i;
        float vals[32];
        if (valid) {
            const float4* p = reinterpret_cast<const float4*>(src + (size_t)v * Dd + s * BK);
#pragma unroll
            for (int k = 0; k < 8; ++k) *reinterpret_cast<float4*>(&vals[4 * k]) = p[k];
        } else {
#pragma unroll
            for (int k = 0; k < 32; ++k) vals[k] = 0.f;
        }
        const size_t chunk = ((size_t)t * NS + s) * CHUNK;
#pragma unroll
        for (int fq = 0; fq < 4; ++fq) {
            _Float16 hi8[8], lo8[8];
#pragma unroll
            for (int e = 0; e < 8; ++e) {
                const float x = vals[fq * 8 + e];
                sq = fmaf(x, x, sq);
                const _Float16 h = (_Float16)x;
                hi8[e] = h;
                lo8[e] = (_Float16)(x - (float)h);
            }
            *reinterpret_cast<f16x8*>(&hp[chunk + fq * (BM * 8) + (size_t)r * 8]) =
                *reinterpret_cast<const f16x8*>(hi8);
            *reinterpret_cast<f16x8*>(&lp[chunk + fq * (BM * 8) + (size_t)r * 8]) =
                *reinterpret_cast<const f16x8*>(lo8);
        }
    }
    sq += __shfl_xor(sq, 1);
    sq += __shfl_xor(sq, 2);
    if (valid && q == 0) sumsq[v] = sq;
}

// ---------------------------------------------------------------------------
// Kernel 2: scores = 2*(A.W^T) - tsq, packed split-f16 MFMA + XCD-chunked map.
// R9-verified: 128x128 tile, 4 waves, K-loop = R5's (250 us); epilogue emits
// per-(row, 64-col-slice) softmax partials via LDS merge.
// ---------------------------------------------------------------------------
__global__ __launch_bounds__(256) void gemm_kernel(const _Float16* __restrict__ Ahp,
                                                   const _Float16* __restrict__ Alp,
                                                   const _Float16* __restrict__ Whp,
                                                   const _Float16* __restrict__ Wlp,
                                                   const float* __restrict__ tsq,
                                                   float* __restrict__ scores,
                                                   float* __restrict__ pmax,
                                                   int*   __restrict__ pidx,
                                                   float* __restrict__ psum) {
    __shared__ __align__(16) char smem_raw[SMEM_BYTES];   // staging | partials (union)
    _Float16 (*lds)[CHUNK] = reinterpret_cast<_Float16(*)[CHUNK]>(smem_raw);

    const int b    = blockIdx.x;
    const int xcd  = b & 7;
    const int slot = b >> 3;
    const int tn   = xcd * 50 + (slot >> 3);   // contiguous tn chunk per XCD
    const int tm   = slot & 7;
    if (tn >= TW) return;

    const int tid  = threadIdx.x;
    const int wid  = tid >> 6;
    const int lane = tid & 63;
    const int wr   = wid >> 1;             // wave row (0..1)
    const int wc   = wid & 1;              // wave col (0..1)
    const int fr   = lane & 15;
    const int fq   = lane >> 4;

    const _Float16* gA_h = Ahp + (size_t)tm * NS * CHUNK;
    const _Float16* gA_l = Alp + (size_t)tm * NS * CHUNK;
    const _Float16* gW_h = Whp + (size_t)tn * NS * CHUNK;
    const _Float16* gW_l = Wlp + (size_t)tn * NS * CHUNK;

    f32x4 acc[4][4];
#pragma unroll
    for (int m = 0; m < 4; ++m)
#pragma unroll
        for (int n = 0; n < 4; ++n) acc[m][n] = (f32x4){0.f, 0.f, 0.f, 0.f};

    for (int s = 0; s < NS; ++s) {
        if (s) __syncthreads();
        const size_t so = (size_t)s * CHUNK;
        const _Float16* gsrc[4] = {gA_h + so, gA_l + so, gW_h + so, gW_l + so};
#pragma unroll
        for (int c = 0; c < 4; ++c) {
#pragma unroll
            for (int i = 0; i < 2; ++i) {
                const int seg = wid * 2 + i;              // 0..7, wave-uniform
                gload_lds16(gsrc[c] + seg * 512 + lane * 8, &lds[c][seg * 512]);
            }
        }
        __syncthreads();

        f16x8 ah[4], al[4];
#pragma unroll
        for (int m = 0; m < 4; ++m) {
            const int r = wr * 64 + m * 16 + fr;
            ah[m] = *reinterpret_cast<const f16x8*>(&lds[0][fq * (BM * 8) + r * 8]);
            al[m] = *reinterpret_cast<const f16x8*>(&lds[1][fq * (BM * 8) + r * 8]);
        }
#pragma unroll
        for (int n = 0; n < 4; ++n) {
            const int c = wc * 64 + n * 16 + fr;
            const f16x8 wh = *reinterpret_cast<const f16x8*>(&lds[2][fq * (BM * 8) + c * 8]);
            const f16x8 wl = *reinterpret_cast<const f16x8*>(&lds[3][fq * (BM * 8) + c * 8]);
#pragma unroll
            for (int m = 0; m < 4; ++m) {
                acc[m][n] = __builtin_amdgcn_mfma_f32_16x16x32_f16(ah[m], wh, acc[m][n], 0, 0, 0);
                acc[m][n] = __builtin_amdgcn_mfma_f32_16x16x32_f16(al[m], wh, acc[m][n], 0, 0, 0);
                acc[m][n] = __builtin_amdgcn_mfma_f32_16x16x32_f16(ah[m], wl, acc[m][n], 0, 0, 0);
            }
        }
    }

    // ------------- epilogue: score stores + LDS softmax partials -------------
    __syncthreads();                       // staging LDS dead -> reuse for partials
    float* pmL = reinterpret_cast<float*>(smem_raw);
    float* psL = pmL + PCOUNT;
    int*   piL = reinterpret_cast<int*>(psL + PCOUNT);

    float tq[4];
    int   gcol[4];
    bool  ok[4];
#pragma unroll
    for (int n = 0; n < 4; ++n) {
        gcol[n] = tn * BN + wc * 64 + n * 16 + fr;
        ok[n]   = gcol[n] < Vv;
        tq[n]   = ok[n] ? tsq[gcol[n]] : 0.f;
    }

#pragma unroll
    for (int m = 0; m < 4; ++m) {
#pragma unroll
        for (int r = 0; r < 4; ++r) {
            const int rloc = wr * 64 + m * 16 + fq * 4 + r;
            const int grow = tm * BM + rloc;
            // pass A: store scores + per-lane max/idx over the 4 n-values
            float vmax = -INFINITY;
            int   vidx = 0x7fffffff;
#pragma unroll
            for (int n = 0; n < 4; ++n) {
                if (ok[n]) {
                    const float sv = fmaf(2.f, acc[m][n][r], -tq[n]);
                    scores[(size_t)grow * Vv + gcol[n]] = sv;
                    if (sv > vmax) { vmax = sv; vidx = gcol[n]; }  // ascending gn
                }
            }
            // pass B: per-lane expsum relative to vmax
            float ls = 0.f;
#pragma unroll
            for (int n = 0; n < 4; ++n) {
                if (ok[n]) {
                    const float sv = fmaf(2.f, acc[m][n][r], -tq[n]);
                    ls += exp2f((sv - vmax) * SC);
                }
            }
            const int o = (rloc * 2 + wc) * PSTRIDE + fr;
            pmL[o] = vmax;
            psL[o] = ls;
            piL[o] = vidx;
        }
    }
    __syncthreads();

    // merge 16 fr-partials per (row, wc-slice); thread t -> (row=t>>1, wcs=t&1)
    {
        const int rloc = tid >> 1;
        const int wcs  = tid & 1;
        float m = -INFINITY, s = 0.f;
        int   id = 0x7fffffff;
#pragma unroll
        for (int f = 0; f < 16; ++f) {
            const int o = (rloc * 2 + wcs) * PSTRIDE + f;
            const float m2 = pmL[o];
            const int   i2 = piL[o];
            const float s2 = psL[o];
            if (m2 > m || (m2 == m && i2 < id)) {
                s = ((m > -INFINITY) ? s * exp2f((m - m2) * SC) : 0.f) + s2;
                m = m2; id = i2;
            } else {
                s += s2 * exp2f((m2 - m) * SC);
            }
        }
        const int grow = tm * BM + rloc;
        const int cidx = tn * 2 + wcs;
        const size_t o = (size_t)grow * NT2 + cidx;
        pmax[o] = m;
        pidx[o] = id;
        psum[o] = s;
    }
}

// ---------------------------------------------------------------------------
// Kernel 3: finalize with integrated per-row stats reduce (R11-verified) +
// single-pass writeout: probs + one-hot + gather W[pred] + copy A row.
// ---------------------------------------------------------------------------
__global__ __launch_bounds__(256) void finalize_kernel(const float* __restrict__ A,
                                                       const float* __restrict__ W,
                                                       const float* __restrict__ pmax,
                                                       const int*   __restrict__ pidx,
                                                       const float* __restrict__ psum,
                                                       float* __restrict__ out0,
                                                       float* __restrict__ out1,
                                                       float* __restrict__ out2,
                                                       float* __restrict__ out3,
                                                       float* __restrict__ out4) {
    const int row = blockIdx.x;
    const int tid = threadIdx.x;
    float* srow = out4 + (size_t)row * Vv;
    float* hrow = out3 + (size_t)row * Vv;
    constexpr int NV4 = Vv >> 2;

    // ---- per-row stats reduce over NT2=786 partials ----
    const size_t base = (size_t)row * NT2;
    float m = -INFINITY, s = 0.f;
    int   id = 0x7fffffff;
    for (int c = tid; c < NT2; c += 256) {
        const float m2 = pmax[base + c];
        const int   i2 = pidx[base + c];
        const float s2 = psum[base + c];
        if (m2 > m || (m2 == m && m2 > -INFINITY && i2 < id)) {
            s = ((m > -INFINITY) ? s * exp2f((m - m2) * SC) : 0.f) + s2;
            m = m2; id = i2;
        } else if (m2 > -INFINITY) {
            s += s2 * exp2f((m2 - m) * SC);
        }
    }
    __shared__ float smax[256];
    __shared__ int   sidx[256];
    __shared__ float ssum[256];
    smax[tid] = m; sidx[tid] = id; ssum[tid] = s;
    __syncthreads();
#pragma unroll
    for (int off = 128; off > 0; off >>= 1) {
        if (tid < off) {
            const float m1 = smax[tid], m2 = smax[tid + off];
            const int   i1 = sidx[tid], i2 = sidx[tid + off];
            const float s1 = ssum[tid], s2 = ssum[tid + off];
            if (m2 > m1 || (m2 == m1 && m2 > -INFINITY && i2 < i1)) {
                smax[tid] = m2; sidx[tid] = i2;
                ssum[tid] = ((m1 > -INFINITY) ? s1 * exp2f((m1 - m2) * SC) : 0.f) + s2;
            } else if (m2 > -INFINITY) {
                ssum[tid] = s1 + s2 * exp2f((m2 - m1) * SC);
            }
        }
        __syncthreads();
    }
    const float gmax = smax[0];
    const int   pred = sidx[0];
    const float inv  = 1.0f / ssum[0];
    __syncthreads();

    // ---- single-pass writeout ----
    const float4* s4 = reinterpret_cast<const float4*>(srow);
    float4* p4 = reinterpret_cast<float4*>(srow);
    float4* h4 = reinterpret_cast<float4*>(hrow);
    for (int i = tid; i < NV4; i += 256) {
        const float4 v = s4[i];
        const int b = 4 * i;
        float4 p, h;
        p.x = exp2f((v.x - gmax) * SC) * inv;
        p.y = exp2f((v.y - gmax) * SC) * inv;
        p.z = exp2f((v.z - gmax) * SC) * inv;
        p.w = exp2f((v.w - gmax) * SC) * inv;
        h.x = (b + 0 == pred) ? 1.f : 0.f;
        h.y = (b + 1 == pred) ? 1.f : 0.f;
        h.z = (b + 2 == pred) ? 1.f : 0.f;
        h.w = (b + 3 == pred) ? 1.f : 0.f;
        p4[i] = p;
        h4[i] = h;
    }
    if (tid == 0) {
        const float val = srow[Vv - 1];
        srow[Vv - 1] = exp2f((val - gmax) * SC) * inv;
        hrow[Vv - 1] = (pred == Vv - 1) ? 1.f : 0.f;
        out2[row] = (float)pred;
    }

    const float4* wrow = reinterpret_cast<const float4*>(W + (size_t)pred * Dd);
    const float4* arow = reinterpret_cast<const float4*>(A + (size_t)row * Dd);
    float4* o0 = reinterpret_cast<float4*>(out0 + (size_t)row * Dd);
    float4* o1 = reinterpret_cast<float4*>(out1 + (size_t)row * Dd);
    if (tid < Dd / 4) {
        o0[tid] = wrow[tid];
        o1[tid] = arow[tid];
    }
}

}  // namespace

extern "C" void kernel_launch(void* const* d_in, const int* in_sizes, int n_in,
                              void* d_out, int out_size, void* d_ws, size_t ws_size,
                              hipStream_t stream) {
    const float* pred_embeds  = (const float*)d_in[0];   // (4,256,768)
    const float* embed_weight = (const float*)d_in[1];   // (50257,768)

    float* out  = (float*)d_out;
    float* out0 = out;                                    // (B,S,D)
    float* out1 = out0 + (size_t)Mm * Dd;                 // (B,S,D)
    float* out2 = out1 + (size_t)Mm * Dd;                 // (B,S)
    float* out3 = out2 + Mm;                              // (B,S,V) one-hot (scratch until finalize)
    float* out4 = out3 + (size_t)Mm * Vv;                 // (B,S,V) probs (scores until finalize)

    // packed scratch inside the out3 region
    _Float16* Whp = (_Float16*)out3;
    _Float16* Wlp = Whp + WPLANE;
    _Float16* Ahp = Wlp + WPLANE;
    _Float16* Alp = Ahp + APLANE;
    float*    tsq = (float*)(Alp + APLANE);
    float*    asq = tsq + Vv;                             // A row-sumsq (unused)
    float*    pmax = asq + Mm;
    int*      pidx = (int*)(pmax + (size_t)Mm * NT2);
    float*    psum = (float*)(pidx + (size_t)Mm * NT2);

    convert_pack_tsq<<<dim3(TW + TA, 2), 256, 0, stream>>>(embed_weight, pred_embeds,
                                                           Whp, Wlp, Ahp, Alp, tsq, asq);

    gemm_kernel<<<3200, 256, 0, stream>>>(Ahp, Alp, Whp, Wlp, tsq, out4,
                                          pmax, pidx, psum);

    finalize_kernel<<<Mm, 256, 0, stream>>>(pred_embeds, embed_weight,
                                            pmax, pidx, psum,
                                            out0, out1, out2, out3, out4);
}